// Round 10
// baseline (115.111 us; speedup 1.0000x reference)
//
#include <hip/hip_runtime.h>
#include <hip/hip_bf16.h>
#include <stdint.h>

// Problem constants
#define BB 2
#define NN 2048
#define DIMM 1024
#define HEADS 16
#define DH 64
#define E3 3072   // 3*DIM
#define LOG2E_ 1.44269504088896f
#define THR_ 8.0f

typedef __bf16 bf16;
typedef __attribute__((ext_vector_type(8))) __bf16 bf16x8;
typedef __attribute__((ext_vector_type(4))) __bf16 bf16x4;
typedef __attribute__((ext_vector_type(4))) float f32x4;

// global -> LDS direct copy, 16B per lane. LDS dest must be wave-uniform base;
// HW adds lane*16. Global src is per-lane.
__device__ __forceinline__ void gload_lds16(const void* gsrc, void* ldst) {
  __builtin_amdgcn_global_load_lds(
      (const __attribute__((address_space(1))) uint32_t*)(uintptr_t)gsrc,
      (__attribute__((address_space(3))) uint32_t*)(uintptr_t)ldst,
      16, 0, 0);
}

// ---------------------------------------------------------------------------
// Kernel 1: fp32 -> bf16 conversion for x, w_qkv, w_out (fused)
// ---------------------------------------------------------------------------
__global__ __launch_bounds__(256)
void convert_all(const float* __restrict__ x, const float* __restrict__ wqkv,
                 const float* __restrict__ wout,
                 bf16* __restrict__ xb, bf16* __restrict__ wqb, bf16* __restrict__ wob) {
  size_t i = (size_t)blockIdx.x * blockDim.x + threadIdx.x;
  const float* src;
  bf16* dst;
  size_t off;
  if (i < 1048576u) { src = x; dst = xb; off = i; }
  else if (i < 1048576u + 786432u) { src = wqkv; dst = wqb; off = i - 1048576u; }
  else { src = wout; dst = wob; off = i - (1048576u + 786432u); }
  float4 v = ((const float4*)src)[off];
  bf16x4 o;
  o[0] = (bf16)v.x; o[1] = (bf16)v.y; o[2] = (bf16)v.z; o[3] = (bf16)v.w;
  *(bf16x4*)(dst + off * 4) = o;
}

// ---------------------------------------------------------------------------
// Kernel 2 (NEW): qkv GEMM — 256x256 tile, BK=32, quad-buffered LDS with
// counted vmcnt (T3/T4): loads stay in flight across barriers, never drained
// to 0 in the main loop. 512 threads = 8 waves (2 M x 4 N), per-wave 128x64
// output (8x4 frags of 16x16x32), 32 MFMA : 12 ds_read_b128 per K-step.
// LDS 128KB: A bufs @ buf*16384 (4 x 16KB), B bufs @ 65536 + buf*16384.
// Rows are [r][4 chunks of 16B], chunk stored at cc ^ ((r ^ (r>>2)) & 3)
// (both-sides swizzle: linear LDS dest + pre-swizzled global src, rule 21).
// C written bf16 with Q cols (n<1024) pre-scaled by 0.125 (exact exp shift).
// ---------------------------------------------------------------------------
#define GDSR(dst, base, off) \
  asm volatile("ds_read_b128 %0, %1 offset:%c2" : "=v"(dst) : "v"(base), "i"(off))

#define GSTAGE(BUF) { \
  gload_lds16(pA0, smem + (BUF)*16384 + w*1024); \
  gload_lds16(pA1, smem + (BUF)*16384 + 8192 + w*1024); \
  gload_lds16(pB0, smem + 65536 + (BUF)*16384 + w*1024); \
  gload_lds16(pB1, smem + 65536 + (BUF)*16384 + 8192 + w*1024); \
  pA0 += 32; pA1 += 32; pB0 += 32; pB1 += 32; }

#define GSTEP(BUF, DOSTAGE, VMC) { \
  if (DOSTAGE) GSTAGE(((BUF)+3)&3); \
  bf16x8 af0, af1, af2, af3, af4, af5, af6, af7, bf0, bf1, bf2, bf3; \
  GDSR(af0, abase, (BUF)*16384 + 0);    GDSR(af1, abase, (BUF)*16384 + 1024); \
  GDSR(af2, abase, (BUF)*16384 + 2048); GDSR(af3, abase, (BUF)*16384 + 3072); \
  GDSR(af4, abase, (BUF)*16384 + 4096); GDSR(af5, abase, (BUF)*16384 + 5120); \
  GDSR(af6, abase, (BUF)*16384 + 6144); GDSR(af7, abase, (BUF)*16384 + 7168); \
  GDSR(bf0, bbase, (BUF)*16384 + 0);    GDSR(bf1, bbase, (BUF)*16384 + 1024); \
  GDSR(bf2, bbase, (BUF)*16384 + 2048); GDSR(bf3, bbase, (BUF)*16384 + 3072); \
  asm volatile("s_waitcnt lgkmcnt(0)" ::: "memory"); \
  __builtin_amdgcn_sched_barrier(0); \
  __builtin_amdgcn_s_setprio(1); \
  acc[0][0]=__builtin_amdgcn_mfma_f32_16x16x32_bf16(af0,bf0,acc[0][0],0,0,0); \
  acc[0][1]=__builtin_amdgcn_mfma_f32_16x16x32_bf16(af0,bf1,acc[0][1],0,0,0); \
  acc[0][2]=__builtin_amdgcn_mfma_f32_16x16x32_bf16(af0,bf2,acc[0][2],0,0,0); \
  acc[0][3]=__builtin_amdgcn_mfma_f32_16x16x32_bf16(af0,bf3,acc[0][3],0,0,0); \
  acc[1][0]=__builtin_amdgcn_mfma_f32_16x16x32_bf16(af1,bf0,acc[1][0],0,0,0); \
  acc[1][1]=__builtin_amdgcn_mfma_f32_16x16x32_bf16(af1,bf1,acc[1][1],0,0,0); \
  acc[1][2]=__builtin_amdgcn_mfma_f32_16x16x32_bf16(af1,bf2,acc[1][2],0,0,0); \
  acc[1][3]=__builtin_amdgcn_mfma_f32_16x16x32_bf16(af1,bf3,acc[1][3],0,0,0); \
  acc[2][0]=__builtin_amdgcn_mfma_f32_16x16x32_bf16(af2,bf0,acc[2][0],0,0,0); \
  acc[2][1]=__builtin_amdgcn_mfma_f32_16x16x32_bf16(af2,bf1,acc[2][1],0,0,0); \
  acc[2][2]=__builtin_amdgcn_mfma_f32_16x16x32_bf16(af2,bf2,acc[2][2],0,0,0); \
  acc[2][3]=__builtin_amdgcn_mfma_f32_16x16x32_bf16(af2,bf3,acc[2][3],0,0,0); \
  acc[3][0]=__builtin_amdgcn_mfma_f32_16x16x32_bf16(af3,bf0,acc[3][0],0,0,0); \
  acc[3][1]=__builtin_amdgcn_mfma_f32_16x16x32_bf16(af3,bf1,acc[3][1],0,0,0); \
  acc[3][2]=__builtin_amdgcn_mfma_f32_16x16x32_bf16(af3,bf2,acc[3][2],0,0,0); \
  acc[3][3]=__builtin_amdgcn_mfma_f32_16x16x32_bf16(af3,bf3,acc[3][3],0,0,0); \
  acc[4][0]=__builtin_amdgcn_mfma_f32_16x16x32_bf16(af4,bf0,acc[4][0],0,0,0); \
  acc[4][1]=__builtin_amdgcn_mfma_f32_16x16x32_bf16(af4,bf1,acc[4][1],0,0,0); \
  acc[4][2]=__builtin_amdgcn_mfma_f32_16x16x32_bf16(af4,bf2,acc[4][2],0,0,0); \
  acc[4][3]=__builtin_amdgcn_mfma_f32_16x16x32_bf16(af4,bf3,acc[4][3],0,0,0); \
  acc[5][0]=__builtin_amdgcn_mfma_f32_16x16x32_bf16(af5,bf0,acc[5][0],0,0,0); \
  acc[5][1]=__builtin_amdgcn_mfma_f32_16x16x32_bf16(af5,bf1,acc[5][1],0,0,0); \
  acc[5][2]=__builtin_amdgcn_mfma_f32_16x16x32_bf16(af5,bf2,acc[5][2],0,0,0); \
  acc[5][3]=__builtin_amdgcn_mfma_f32_16x16x32_bf16(af5,bf3,acc[5][3],0,0,0); \
  acc[6][0]=__builtin_amdgcn_mfma_f32_16x16x32_bf16(af6,bf0,acc[6][0],0,0,0); \
  acc[6][1]=__builtin_amdgcn_mfma_f32_16x16x32_bf16(af6,bf1,acc[6][1],0,0,0); \
  acc[6][2]=__builtin_amdgcn_mfma_f32_16x16x32_bf16(af6,bf2,acc[6][2],0,0,0); \
  acc[6][3]=__builtin_amdgcn_mfma_f32_16x16x32_bf16(af6,bf3,acc[6][3],0,0,0); \
  acc[7][0]=__builtin_amdgcn_mfma_f32_16x16x32_bf16(af7,bf0,acc[7][0],0,0,0); \
  acc[7][1]=__builtin_amdgcn_mfma_f32_16x16x32_bf16(af7,bf1,acc[7][1],0,0,0); \
  acc[7][2]=__builtin_amdgcn_mfma_f32_16x16x32_bf16(af7,bf2,acc[7][2],0,0,0); \
  acc[7][3]=__builtin_amdgcn_mfma_f32_16x16x32_bf16(af7,bf3,acc[7][3],0,0,0); \
  __builtin_amdgcn_s_setprio(0); \
  if ((VMC) == 8)      { asm volatile("s_waitcnt vmcnt(8)" ::: "memory"); } \
  else if ((VMC) == 4) { asm volatile("s_waitcnt vmcnt(4)" ::: "memory"); } \
  else if ((VMC) == 0) { asm volatile("s_waitcnt vmcnt(0)" ::: "memory"); } \
  if ((VMC) >= 0) { \
    __builtin_amdgcn_sched_barrier(0); \
    __builtin_amdgcn_s_barrier(); \
  } }

__global__ __launch_bounds__(512, 2)
void gemm_qkv(const bf16* __restrict__ A, const bf16* __restrict__ Bw,
              bf16* __restrict__ C) {
  int bid = blockIdx.x;                 // 0..191
  bid = (bid & 7) * 24 + (bid >> 3);    // XCD chunk swizzle (192 % 8 == 0)
  const int nx = bid % 12;
  const int ny = bid / 12;
  const int m0 = ny * 256, n0 = nx * 256;
  const int tid = threadIdx.x;
  const int w = tid >> 6, lane = tid & 63, c = lane & 15, g = lane >> 4;
  const int wr = w >> 2, wc = w & 3;

  __shared__ __align__(16) char smem[131072];
  const uint32_t smem32 = (uint32_t)(uintptr_t)smem;
  const int swzc = (c ^ (c >> 2)) & 3;
  const uint32_t abase = smem32 + (wr * 128 + c) * 64 + ((g ^ swzc) * 16);
  const uint32_t bbase = smem32 + 65536 + (wc * 64 + c) * 64 + ((g ^ swzc) * 16);

  // staging source pointers (per-thread; dest slot -> pre-swizzled src chunk)
  const bf16 *pA0, *pA1, *pB0, *pB1;
  {
    int s0 = w * 1024 + lane * 16, s1 = 8192 + w * 1024 + lane * 16;
    int r0 = s0 >> 6, cs0 = (s0 >> 4) & 3;
    int r1 = s1 >> 6, cs1 = (s1 >> 4) & 3;
    int k0 = (cs0 ^ ((r0 ^ (r0 >> 2)) & 3)) * 8;
    int k1 = (cs1 ^ ((r1 ^ (r1 >> 2)) & 3)) * 8;
    pA0 = A + (size_t)(m0 + r0) * 1024 + k0;
    pA1 = A + (size_t)(m0 + r1) * 1024 + k1;
    pB0 = Bw + (size_t)(n0 + r0) * 1024 + k0;
    pB1 = Bw + (size_t)(n0 + r1) * 1024 + k1;
  }

  f32x4 acc[8][4] = {};

  // prologue: stage K-tiles 0,1,2 into bufs 0,1,2; wait tile 0 (8 in flight)
  GSTAGE(0); GSTAGE(1); GSTAGE(2);
  asm volatile("s_waitcnt vmcnt(8)" ::: "memory");
  __builtin_amdgcn_sched_barrier(0);
  __builtin_amdgcn_s_barrier();

  // t = 0..27 (stage t+3, keep 8 loads in flight across each barrier)
  for (int u = 0; u < 7; ++u) {
    GSTEP(0, 1, 8) GSTEP(1, 1, 8) GSTEP(2, 1, 8) GSTEP(3, 1, 8)
  }
  GSTEP(0, 1, 8)   // t=28 (stages tile 31 -> buf 3)
  GSTEP(1, 0, 4)   // t=29 (drain: tile 30 ready)
  GSTEP(2, 0, 0)   // t=30 (drain: tile 31 ready)
  GSTEP(3, 0, -1)  // t=31 (nothing outstanding)

  // epilogue: C[row][col], C/D frag layout col=lane&15, row=(lane>>4)*4+reg
  const float qsc = (n0 < 1024) ? 0.125f : 1.0f;
#pragma unroll
  for (int fr = 0; fr < 8; ++fr) {
    const int row = m0 + wr * 128 + fr * 16 + g * 4;
#pragma unroll
    for (int fc = 0; fc < 4; ++fc) {
      const int col = n0 + wc * 64 + fc * 16 + c;
#pragma unroll
      for (int r = 0; r < 4; ++r)
        C[(size_t)(row + r) * E3 + col] = (bf16)(acc[fr][fc][r] * qsc);
    }
  }
}

// ---------------------------------------------------------------------------
// Kernel 4: out GEMM (128x128 tile, m97 structure) — unchanged.
// ---------------------------------------------------------------------------
template <int OUTMODE>
__global__ __launch_bounds__(256)
void gemm_bt(const bf16* __restrict__ A, const bf16* __restrict__ Bw,
             void* __restrict__ Cout, const float* __restrict__ bias, int ldc) {
  const int tid = threadIdx.x;
  const int w = tid >> 6;
  const int lane = tid & 63;
  const int c = lane & 15;
  const int g = lane >> 4;
  const int wr = w >> 1, wc = w & 1;
  const int m0 = blockIdx.y * 128;
  const int n0 = blockIdx.x * 128;

  __shared__ __align__(16) char smem[16384];
  char* As = smem;
  char* Bs = smem + 8192;

  f32x4 acc[4][4] = {};

  for (int kt = 0; kt < 1024; kt += 32) {
    __syncthreads();
#pragma unroll
    for (int it = 0; it < 2; ++it) {
      int t = it * 256 + tid;
      int row = t >> 2, cc = t & 3;
      gload_lds16(A + (size_t)(m0 + row) * 1024 + kt + cc * 8, As + it * 4096 + w * 1024);
      gload_lds16(Bw + (size_t)(n0 + row) * 1024 + kt + cc * 8, Bs + it * 4096 + w * 1024);
    }
    __syncthreads();

    bf16x8 af[4], bfr[4];
#pragma unroll
    for (int i = 0; i < 4; ++i)
      af[i] = *(const bf16x8*)(As + ((wr * 64 + i * 16 + c) * 32 + g * 8) * 2);
#pragma unroll
    for (int j = 0; j < 4; ++j)
      bfr[j] = *(const bf16x8*)(Bs + ((wc * 64 + j * 16 + c) * 32 + g * 8) * 2);
#pragma unroll
    for (int i = 0; i < 4; ++i)
#pragma unroll
      for (int j = 0; j < 4; ++j)
        acc[i][j] = __builtin_amdgcn_mfma_f32_16x16x32_bf16(af[i], bfr[j], acc[i][j], 0, 0, 0);
  }

  if (OUTMODE == 0) {
    const float qsc = (n0 < 1024) ? 0.125f : 1.0f;
    bf16* Cc = (bf16*)Cout;
#pragma unroll
    for (int i = 0; i < 4; ++i) {
      int row = m0 + wr * 64 + i * 16 + g * 4;
#pragma unroll
      for (int j = 0; j < 4; ++j) {
        int col = n0 + wc * 64 + j * 16 + c;
#pragma unroll
        for (int r = 0; r < 4; ++r)
          Cc[(size_t)(row + r) * ldc + col] = (bf16)(acc[i][j][r] * qsc);
      }
    }
  } else {
    float* Cc = (float*)Cout;
#pragma unroll
    for (int i = 0; i < 4; ++i) {
      int row = m0 + wr * 64 + i * 16 + g * 4;
#pragma unroll
      for (int j = 0; j < 4; ++j) {
        int col = n0 + wc * 64 + j * 16 + c;
        float bv = bias[col];
#pragma unroll
        for (int r = 0; r < 4; ++r)
          Cc[(size_t)(row + r) * ldc + col] = acc[i][j][r] + bv;
      }
    }
  }
}

// ---------------------------------------------------------------------------
// Kernel 3: fused flash attention — swapped-operand, 2-deep pipeline (T15).
// Unchanged from round 9 (passed @56.6us).
// ---------------------------------------------------------------------------
#define DSR128(dst, base, off) \
  asm volatile("ds_read_b128 %0, %1 offset:%c2" : "=v"(dst) : "v"(base), "i"(off))
#define DSTR(dst, base, off) \
  asm volatile("ds_read_b64_tr_b16 %0, %1 offset:%c2" : "=v"(dst) : "v"(base), "i"(off))

#define KF_ALL(KB) \
  DSR128(kf[0][0], kb0, (KB)*8192 + 0);    DSR128(kf[0][1], kb1, (KB)*8192 + 0); \
  DSR128(kf[1][0], kb0, (KB)*8192 + 2048); DSR128(kf[1][1], kb1, (KB)*8192 + 2048); \
  DSR128(kf[2][0], kb0, (KB)*8192 + 4096); DSR128(kf[2][1], kb1, (KB)*8192 + 4096); \
  DSR128(kf[3][0], kb0, (KB)*8192 + 6144); DSR128(kf[3][1], kb1, (KB)*8192 + 6144);

#define TRPAIR(f, ks, VP) \
  DSTR(tlo[f][ks], tb, (VP)*8192 + (f)*2048 + (ks)*1024); \
  DSTR(thi[f][ks], tb, (VP)*8192 + (f)*2048 + (ks)*1024 + 512);
#define TR_ALL(VP) \
  TRPAIR(0,0,VP) TRPAIR(0,1,VP) TRPAIR(1,0,VP) TRPAIR(1,1,VP) \
  TRPAIR(2,0,VP) TRPAIR(2,1,VP) TRPAIR(3,0,VP) TRPAIR(3,1,VP)

#define SMAX_A(SPRV, qc) { \
  f32x4 vm = SPRV[0][qc]; \
  _Pragma("unroll") for (int j = 1; j < 4; ++j) \
    _Pragma("unroll") for (int r = 0; r < 4; ++r) vm[r] = fmaxf(vm[r], SPRV[j][qc][r]); \
  float rmax = fmaxf(fmaxf(vm[0], vm[1]), fmaxf(vm[2], vm[3])); \
  rmax = fmaxf(rmax, __shfl_xor(rmax, 16, 64)); \
  rmax = fmaxf(rmax, __shfl_xor(rmax, 32, 64)); \
  const float rmax2 = rmax * LOG2E_; \
  if (!__all(rmax2 <= mrun[qc] + THR_)) { \
    const float mnew = fmaxf(mrun[qc], rmax2); \
    const float fac = __builtin_amdgcn_exp2f(mrun[qc] - mnew); \
    mrun[qc] = mnew; \
    _Pragma("unroll") for (int f = 0; f < 4; ++f) oacc[f][qc] *= fac; \
    lacc[qc] *= fac; \
  } }

#define SMAX_B(SPRV, qc) { \
  const float negm = -mrun[qc]; \
  f32x4 p[4]; \
  _Pragma("unroll") for (int j = 0; j < 4; ++j) \
    _Pragma("unroll") for (int r = 0; r < 4; ++r) \
      p[j][r] = __builtin_amdgcn_exp2f(fmaf(SPRV[j][qc][r], LOG2E_, negm)); \
  _Pragma("unroll") for (int ks = 0; ks < 2; ++ks) \
    _Pragma("unroll") for (int r = 0; r < 4; ++r) { \
      vb[qc][ks][r] = (bf16)p[ks][r]; vb[qc][ks][4 + r] = (bf16)p[ks + 2][r]; \
    } }

#define QK_ALL(SCUR) \
  _Pragma("unroll") for (int j = 0; j < 4; ++j) { \
    f32x4 z = {0.f, 0.f, 0.f, 0.f}; \
    f32x4 s0 = __builtin_amdgcn_mfma_f32_16x16x32_bf16(kf[j][0], qf[0][0], z, 0, 0, 0); \
    s0 = __builtin_amdgcn_mfma_f32_16x16x32_bf16(kf[j][1], qf[0][1], s0, 0, 0, 0); \
    SCUR[j][0] = s0; \
    f32x4 s1 = __builtin_amdgcn_mfma_f32_16x16x32_bf16(kf[j][0], qf[1][0], z, 0, 0, 0); \
    s1 = __builtin_amdgcn_mfma_f32_16x16x32_bf16(kf[j][1], qf[1][1], s1, 0, 0, 0); \
    SCUR[j][1] = s1; }

#define PV_ALL() \
  _Pragma("unroll") for (int f = 0; f < 4; ++f) \
    _Pragma("unroll") for (int ks = 0; ks < 2; ++ks) { \
      bf16x8 va; \
      _Pragma("unroll") for (int e = 0; e < 4; ++e) { va[e] = tlo[f][ks][e]; va[4+e] = thi[f][ks][e]; } \
      oacc[f][0] = __builtin_amdgcn_mfma_f32_16x16x32_bf16(va, vb[0][ks], oacc[f][0], 0, 0, 0); \
      oacc[f][1] = __builtin_amdgcn_mfma_f32_16x16x32_bf16(va, vb[1][ks], oacc[f][1], 0, 0, 0); \
    } \
  lacc[0] = __builtin_amdgcn_mfma_f32_16x16x32_bf16(ones, vb[0][0], lacc[0], 0, 0, 0); \
  lacc[0] = __builtin_amdgcn_mfma_f32_16x16x32_bf16(ones, vb[0][1], lacc[0], 0, 0, 0); \
  lacc[1] = __builtin_amdgcn_mfma_f32_16x16x32_bf16(ones, vb[1][0], lacc[1], 0, 0, 0); \
  lacc[1] = __builtin_amdgcn_mfma_f32_16x16x32_bf16(ones, vb[1][1], lacc[1], 0, 0, 0);

#define STEP(KB, VN, VP, SCUR, SPRV, DOSTAGE, DOPREV) { \
  if (DOSTAGE) { \
    gload_lds16(pK0, smem + ((KB)^1)*8192 + w*1024); \
    gload_lds16(pK1, smem + ((KB)^1)*8192 + 4096 + w*1024); \
    gload_lds16(pV0, smem + 16384 + (VN)*8192 + w*1024); \
    gload_lds16(pV1, smem + 16384 + (VN)*8192 + 4096 + w*1024); \
    pK0 += 64*E3; pK1 += 64*E3; pV0 += 64*E3; pV1 += 64*E3; \
  } \
  if (DOPREV) { SMAX_A(SPRV, 0); SMAX_A(SPRV, 1); } \
  __builtin_amdgcn_sched_barrier(0); \
  KF_ALL(KB); \
  if (DOPREV) { TR_ALL(VP); } \
  if (DOPREV) { SMAX_B(SPRV, 0); SMAX_B(SPRV, 1); } \
  if (DOPREV) { asm volatile("s_waitcnt lgkmcnt(15)" ::: "memory"); } \
  else        { asm volatile("s_waitcnt lgkmcnt(0)" ::: "memory"); } \
  __builtin_amdgcn_sched_barrier(0); \
  __builtin_amdgcn_s_setprio(1); \
  QK_ALL(SCUR); \
  __builtin_amdgcn_s_setprio(0); \
  if (DOPREV) { \
    asm volatile("s_waitcnt lgkmcnt(0)" ::: "memory"); \
    __builtin_amdgcn_sched_barrier(0); \
    __builtin_amdgcn_s_setprio(1); \
    PV_ALL(); \
    __builtin_amdgcn_s_setprio(0); \
  } \
  __syncthreads(); \
}

__global__ __launch_bounds__(256, 2)
void flash_attn(const bf16* __restrict__ qkv, bf16* __restrict__ attb) {
  int bid = blockIdx.x;
  bid = (bid & 7) * 64 + (bid >> 3);  // XCD chunk swizzle (512 % 8 == 0)
  const int tid = threadIdx.x;
  const int w = tid >> 6;
  const int lane = tid & 63;
  const int c = lane & 15;
  const int g = lane >> 4;
  const int qt = bid & 15;            // 16 q-tiles of 128 rows
  const int bh = bid >> 4;
  const int b = bh >> 4;
  const int h = bh & 15;
  const int q0 = qt * 128 + w * 32;

  __shared__ __align__(16) char smem[49152];
  const uint32_t smem32 = (uint32_t)(uintptr_t)smem;

  const uint32_t kb0 = smem32 + c * 128 + ((g ^ (c & 7)) * 16);
  const uint32_t kb1 = smem32 + c * 128 + (((4 + g) ^ (c & 7)) * 16);
  const uint32_t tb  = smem32 + 16384 + lane * 8;

  bf16x8 qf[2][2];
#pragma unroll
  for (int qc = 0; qc < 2; ++qc) {
    const size_t qbase = (size_t)(b * NN + q0 + qc * 16 + c) * E3 + h * 64;
    qf[qc][0] = *(const bf16x8*)(qkv + qbase + g * 8);
    qf[qc][1] = *(const bf16x8*)(qkv + qbase + 32 + g * 8);
  }

  bf16x8 ones;
#pragma unroll
  for (int e = 0; e < 8; ++e) ones[e] = (bf16)1.0f;

  const bf16 *pK0, *pK1, *pV0, *pV1;
  {
    int tK0 = tid, tK1 = 256 + tid;
    int r0 = tK0 >> 3, s0 = (tK0 & 7) ^ (r0 & 7);
    int r1 = tK1 >> 3, s1 = (tK1 & 7) ^ (r1 & 7);
    pK0 = qkv + (size_t)(b * NN + r0) * E3 + 1024 + h * 64 + s0 * 8;
    pK1 = qkv + (size_t)(b * NN + r1) * E3 + 1024 + h * 64 + s1 * 8;
    int sv0 = tid, sv1 = 256 + tid;
    int f0 = sv0 >> 7, ks0 = (sv0 >> 6) & 1, o0 = (sv0 >> 5) & 1,
        g0 = (sv0 >> 3) & 3, j0 = (sv0 >> 1) & 3, i0 = sv0 & 1;
    int f1 = sv1 >> 7, ks1 = (sv1 >> 6) & 1, o1 = (sv1 >> 5) & 1,
        g1 = (sv1 >> 3) & 3, j1 = (sv1 >> 1) & 3, i1 = sv1 & 1;
    int key0 = 32 * o0 + 16 * ks0 + 4 * g0 + j0;
    int key1 = 32 * o1 + 16 * ks1 + 4 * g1 + j1;
    pV0 = qkv + (size_t)(b * NN + key0) * E3 + 2048 + h * 64 + f0 * 16 + i0 * 8;
    pV1 = qkv + (size_t)(b * NN + key1) * E3 + 2048 + h * 64 + f1 * 16 + i1 * 8;
  }

  f32x4 oacc[4][2] = {};
  f32x4 lacc[2] = {};
  float mrun[2] = {-1e30f, -1e30f};
  f32x4 sA[4][2], sB[4][2];
  bf16x8 kf[4][2];
  bf16x4 tlo[4][2], thi[4][2];
  bf16x8 vb[2][2];

  gload_lds16(pK0, smem + w * 1024);
  gload_lds16(pK1, smem + 4096 + w * 1024);
  gload_lds16(pV0, smem + 16384 + w * 1024);
  gload_lds16(pV1, smem + 16384 + 4096 + w * 1024);
  pK0 += 64 * E3; pK1 += 64 * E3; pV0 += 64 * E3; pV1 += 64 * E3;
  __syncthreads();

  STEP(0, 1, 0, sA, sB, 1, 0)                 // t = 0
  for (int to = 1; to <= 25; to += 4) {
    STEP(1, 2, 0, sB, sA, 1, 1)               // t ≡ 1 (mod 4)
    STEP(0, 3, 1, sA, sB, 1, 1)               // t ≡ 2
    STEP(1, 0, 2, sB, sA, 1, 1)               // t ≡ 3
    STEP(0, 1, 3, sA, sB, 1, 1)               // t ≡ 0
  }
  STEP(1, 2, 0, sB, sA, 1, 1)                 // t = 29
  STEP(0, 3, 1, sA, sB, 1, 1)                 // t = 30
  STEP(1, 0, 2, sB, sA, 0, 1)                 // t = 31 (no stage)

  SMAX_A(sB, 0); SMAX_A(sB, 1);
  TR_ALL(3);
  SMAX_B(sB, 0); SMAX_B(sB, 1);
  asm volatile("s_waitcnt lgkmcnt(0)" ::: "memory");
  __builtin_amdgcn_sched_barrier(0);
  PV_ALL();

#pragma unroll
  for (int qc = 0; qc < 2; ++qc) {
    const float inv = __builtin_amdgcn_rcpf(lacc[qc][0]);
    const size_t row = (size_t)(b * NN + q0 + qc * 16 + c);
#pragma unroll
    for (int f = 0; f < 4; ++f) {
      bf16x4 o;
#pragma unroll
      for (int r = 0; r < 4; ++r) o[r] = (bf16)(oacc[f][qc][r] * inv);
      *(bf16x4*)(attb + row * 1024 + h * 64 + f * 16 + 4 * g) = o;
    }
  }
}

// ---------------------------------------------------------------------------
extern "C" void kernel_launch(void* const* d_in, const int* in_sizes, int n_in,
                              void* d_out, int out_size, void* d_ws, size_t ws_size,
                              hipStream_t stream) {
  const float* x = (const float*)d_in[0];
  const float* wqkv = (const float*)d_in[1];
  const float* wout = (const float*)d_in[2];
  const float* bout = (const float*)d_in[3];

  char* ws = (char*)d_ws;
  bf16* xb   = (bf16*)(ws);
  bf16* wqb  = (bf16*)(ws + 8388608);
  bf16* wob  = (bf16*)(ws + 14680064);
  bf16* qkvb = (bf16*)(ws + 16777216);
  bf16* attb = (bf16*)(ws + 41943040);

  convert_all<<<8192, 256, 0, stream>>>(x, wqkv, wout, xb, wqb, wob);
  gemm_qkv<<<192, 512, 0, stream>>>(xb, wqb, qkvb);
  flash_attn<<<512, 256, 0, stream>>>(qkvb, attb);
  gemm_bt<1><<<dim3(8, 32), 256, 0, stream>>>(attb, wob, d_out, bout, DIMM);
}

// Round 11
// 110.900 us; speedup vs baseline: 1.0380x; 1.0380x over previous
//
#include <hip/hip_runtime.h>
#include <hip/hip_bf16.h>
#include <stdint.h>

// Problem constants
#define BB 2
#define NN 2048
#define DIMM 1024
#define HEADS 16
#define DH 64
#define E3 3072   // 3*DIM
#define LOG2E_ 1.44269504088896f
#define THR_ 8.0f

typedef __bf16 bf16;
typedef __attribute__((ext_vector_type(8))) __bf16 bf16x8;
typedef __attribute__((ext_vector_type(4))) __bf16 bf16x4;
typedef __attribute__((ext_vector_type(4))) float f32x4;

// global -> LDS direct copy, 16B per lane. LDS dest must be wave-uniform base;
// HW adds lane*16. Global src is per-lane.
__device__ __forceinline__ void gload_lds16(const void* gsrc, void* ldst) {
  __builtin_amdgcn_global_load_lds(
      (const __attribute__((address_space(1))) uint32_t*)(uintptr_t)gsrc,
      (__attribute__((address_space(3))) uint32_t*)(uintptr_t)ldst,
      16, 0, 0);
}

// ---------------------------------------------------------------------------
// Kernel 1: fp32 -> bf16 conversion for x, w_qkv, w_out (fused)
// ---------------------------------------------------------------------------
__global__ __launch_bounds__(256)
void convert_all(const float* __restrict__ x, const float* __restrict__ wqkv,
                 const float* __restrict__ wout,
                 bf16* __restrict__ xb, bf16* __restrict__ wqb, bf16* __restrict__ wob) {
  size_t i = (size_t)blockIdx.x * blockDim.x + threadIdx.x;
  const float* src;
  bf16* dst;
  size_t off;
  if (i < 1048576u) { src = x; dst = xb; off = i; }
  else if (i < 1048576u + 786432u) { src = wqkv; dst = wqb; off = i - 1048576u; }
  else { src = wout; dst = wob; off = i - (1048576u + 786432u); }
  float4 v = ((const float4*)src)[off];
  bf16x4 o;
  o[0] = (bf16)v.x; o[1] = (bf16)v.y; o[2] = (bf16)v.z; o[3] = (bf16)v.w;
  *(bf16x4*)(dst + off * 4) = o;
}

// ---------------------------------------------------------------------------
// Kernel 2: qkv GEMM — 256x256 tile, BK=64 (128B rows), double-buffered.
// Swizzle = flash's proven pattern: 8 chunks of 16B per row, stored chunk =
// cc ^ (row & 7), both-sides (pre-swizzled global src + XOR'd ds_read base).
// 512 thr = 8 waves (2M x 4N); per-wave output 128x64 = 8x4 frags; per
// K-step 64 MFMA : 24 ds_read_b128. Counted waits, raw s_barrier (1/step).
// LDS 128KB: A bufs @ 0/32768, B bufs @ 65536/98304.
// ---------------------------------------------------------------------------
#define GDSR(dst, base, off) \
  asm volatile("ds_read_b128 %0, %1 offset:%c2" : "=v"(dst) : "v"(base), "i"(off))

#define GRD12(ABASE, BBASE, OFF) \
  GDSR(af0, ABASE, (OFF));        GDSR(af1, ABASE, (OFF)+2048); \
  GDSR(af2, ABASE, (OFF)+4096);   GDSR(af3, ABASE, (OFF)+6144); \
  GDSR(af4, ABASE, (OFF)+8192);   GDSR(af5, ABASE, (OFF)+10240); \
  GDSR(af6, ABASE, (OFF)+12288);  GDSR(af7, ABASE, (OFF)+14336); \
  GDSR(bf0, BBASE, (OFF));        GDSR(bf1, BBASE, (OFF)+2048); \
  GDSR(bf2, BBASE, (OFF)+4096);   GDSR(bf3, BBASE, (OFF)+6144);

#define GMM32() \
  acc[0][0]=__builtin_amdgcn_mfma_f32_16x16x32_bf16(af0,bf0,acc[0][0],0,0,0); \
  acc[0][1]=__builtin_amdgcn_mfma_f32_16x16x32_bf16(af0,bf1,acc[0][1],0,0,0); \
  acc[0][2]=__builtin_amdgcn_mfma_f32_16x16x32_bf16(af0,bf2,acc[0][2],0,0,0); \
  acc[0][3]=__builtin_amdgcn_mfma_f32_16x16x32_bf16(af0,bf3,acc[0][3],0,0,0); \
  acc[1][0]=__builtin_amdgcn_mfma_f32_16x16x32_bf16(af1,bf0,acc[1][0],0,0,0); \
  acc[1][1]=__builtin_amdgcn_mfma_f32_16x16x32_bf16(af1,bf1,acc[1][1],0,0,0); \
  acc[1][2]=__builtin_amdgcn_mfma_f32_16x16x32_bf16(af1,bf2,acc[1][2],0,0,0); \
  acc[1][3]=__builtin_amdgcn_mfma_f32_16x16x32_bf16(af1,bf3,acc[1][3],0,0,0); \
  acc[2][0]=__builtin_amdgcn_mfma_f32_16x16x32_bf16(af2,bf0,acc[2][0],0,0,0); \
  acc[2][1]=__builtin_amdgcn_mfma_f32_16x16x32_bf16(af2,bf1,acc[2][1],0,0,0); \
  acc[2][2]=__builtin_amdgcn_mfma_f32_16x16x32_bf16(af2,bf2,acc[2][2],0,0,0); \
  acc[2][3]=__builtin_amdgcn_mfma_f32_16x16x32_bf16(af2,bf3,acc[2][3],0,0,0); \
  acc[3][0]=__builtin_amdgcn_mfma_f32_16x16x32_bf16(af3,bf0,acc[3][0],0,0,0); \
  acc[3][1]=__builtin_amdgcn_mfma_f32_16x16x32_bf16(af3,bf1,acc[3][1],0,0,0); \
  acc[3][2]=__builtin_amdgcn_mfma_f32_16x16x32_bf16(af3,bf2,acc[3][2],0,0,0); \
  acc[3][3]=__builtin_amdgcn_mfma_f32_16x16x32_bf16(af3,bf3,acc[3][3],0,0,0); \
  acc[4][0]=__builtin_amdgcn_mfma_f32_16x16x32_bf16(af4,bf0,acc[4][0],0,0,0); \
  acc[4][1]=__builtin_amdgcn_mfma_f32_16x16x32_bf16(af4,bf1,acc[4][1],0,0,0); \
  acc[4][2]=__builtin_amdgcn_mfma_f32_16x16x32_bf16(af4,bf2,acc[4][2],0,0,0); \
  acc[4][3]=__builtin_amdgcn_mfma_f32_16x16x32_bf16(af4,bf3,acc[4][3],0,0,0); \
  acc[5][0]=__builtin_amdgcn_mfma_f32_16x16x32_bf16(af5,bf0,acc[5][0],0,0,0); \
  acc[5][1]=__builtin_amdgcn_mfma_f32_16x16x32_bf16(af5,bf1,acc[5][1],0,0,0); \
  acc[5][2]=__builtin_amdgcn_mfma_f32_16x16x32_bf16(af5,bf2,acc[5][2],0,0,0); \
  acc[5][3]=__builtin_amdgcn_mfma_f32_16x16x32_bf16(af5,bf3,acc[5][3],0,0,0); \
  acc[6][0]=__builtin_amdgcn_mfma_f32_16x16x32_bf16(af6,bf0,acc[6][0],0,0,0); \
  acc[6][1]=__builtin_amdgcn_mfma_f32_16x16x32_bf16(af6,bf1,acc[6][1],0,0,0); \
  acc[6][2]=__builtin_amdgcn_mfma_f32_16x16x32_bf16(af6,bf2,acc[6][2],0,0,0); \
  acc[6][3]=__builtin_amdgcn_mfma_f32_16x16x32_bf16(af6,bf3,acc[6][3],0,0,0); \
  acc[7][0]=__builtin_amdgcn_mfma_f32_16x16x32_bf16(af7,bf0,acc[7][0],0,0,0); \
  acc[7][1]=__builtin_amdgcn_mfma_f32_16x16x32_bf16(af7,bf1,acc[7][1],0,0,0); \
  acc[7][2]=__builtin_amdgcn_mfma_f32_16x16x32_bf16(af7,bf2,acc[7][2],0,0,0); \
  acc[7][3]=__builtin_amdgcn_mfma_f32_16x16x32_bf16(af7,bf3,acc[7][3],0,0,0);

#define GSTAGE(BUF) { \
  gload_lds16(pA,          smem + (BUF)*32768 + w*1024); \
  gload_lds16(pA + 65536,  smem + (BUF)*32768 + 8192 + w*1024); \
  gload_lds16(pA + 131072, smem + (BUF)*32768 + 16384 + w*1024); \
  gload_lds16(pA + 196608, smem + (BUF)*32768 + 24576 + w*1024); \
  gload_lds16(pB,          smem + 65536 + (BUF)*32768 + w*1024); \
  gload_lds16(pB + 65536,  smem + 65536 + (BUF)*32768 + 8192 + w*1024); \
  gload_lds16(pB + 131072, smem + 65536 + (BUF)*32768 + 16384 + w*1024); \
  gload_lds16(pB + 196608, smem + 65536 + (BUF)*32768 + 24576 + w*1024); \
  pA += 64; pB += 64; }

#define GSTEP(BUF, DOSTAGE) { \
  bf16x8 af0, af1, af2, af3, af4, af5, af6, af7, bf0, bf1, bf2, bf3; \
  GRD12(abase0, bbase0, (BUF)*32768); \
  if (DOSTAGE) { GSTAGE((BUF)^1); } \
  asm volatile("s_waitcnt lgkmcnt(0)" ::: "memory"); \
  __builtin_amdgcn_sched_barrier(0); \
  __builtin_amdgcn_s_setprio(1); \
  GMM32(); \
  __builtin_amdgcn_s_setprio(0); \
  GRD12(abase1, bbase1, (BUF)*32768); \
  asm volatile("s_waitcnt lgkmcnt(0)" ::: "memory"); \
  __builtin_amdgcn_sched_barrier(0); \
  __builtin_amdgcn_s_setprio(1); \
  GMM32(); \
  __builtin_amdgcn_s_setprio(0); \
  if (DOSTAGE) { asm volatile("s_waitcnt vmcnt(0)" ::: "memory"); } \
  __builtin_amdgcn_sched_barrier(0); \
  __builtin_amdgcn_s_barrier(); \
}

__global__ __launch_bounds__(512, 2)
void gemm_qkv(const bf16* __restrict__ A, const bf16* __restrict__ Bw,
              bf16* __restrict__ C) {
  int bid = blockIdx.x;                 // 0..191
  bid = (bid & 7) * 24 + (bid >> 3);    // XCD chunk swizzle (192 % 8 == 0)
  const int nx = bid % 12;
  const int ny = bid / 12;
  const int m0 = ny * 256, n0 = nx * 256;
  const int tid = threadIdx.x;
  const int w = tid >> 6, lane = tid & 63, c = lane & 15, g = lane >> 4;
  const int wr = w >> 2, wc = w & 3;

  __shared__ __align__(16) char smem[131072];
  const uint32_t smem32 = (uint32_t)(uintptr_t)smem;
  // ds_read bases (flash kb0/kb1 pattern): row*128 + ((kd*4+g) ^ (row&7))*16,
  // row&7 == c&7 since frag/wave row offsets are multiples of 8.
  const uint32_t abase0 = smem32 + (wr * 128 + c) * 128 + ((g ^ (c & 7)) * 16);
  const uint32_t abase1 = smem32 + (wr * 128 + c) * 128 + (((4 + g) ^ (c & 7)) * 16);
  const uint32_t bbase0 = smem32 + 65536 + (wc * 64 + c) * 128 + ((g ^ (c & 7)) * 16);
  const uint32_t bbase1 = smem32 + 65536 + (wc * 64 + c) * 128 + (((4 + g) ^ (c & 7)) * 16);

  // staging source pointers: dest byte d = it*8192 + tid*16 ->
  // row = it*64 + (tid>>3), stored chunk = tid&7, logical chunk
  // cc = (tid&7) ^ ((tid>>3)&7)  (it-independent).
  const bf16 *pA, *pB;
  {
    const int r0 = tid >> 3;
    const int cc = (tid & 7) ^ ((tid >> 3) & 7);
    pA = A + (size_t)(m0 + r0) * 1024 + cc * 8;
    pB = Bw + (size_t)(n0 + r0) * 1024 + cc * 8;
  }

  f32x4 acc[8][4] = {};

  // prologue: stage K-tile 0 into buf 0
  GSTAGE(0);
  asm volatile("s_waitcnt vmcnt(0)" ::: "memory");
  __builtin_amdgcn_sched_barrier(0);
  __builtin_amdgcn_s_barrier();

  for (int u = 0; u < 7; ++u) {   // t = 0..13
    GSTEP(0, 1) GSTEP(1, 1)
  }
  GSTEP(0, 1)   // t = 14 (stages tile 15 -> buf 1)
  GSTEP(1, 0)   // t = 15

  // epilogue: C/D frag layout col = lane&15, row = (lane>>4)*4 + reg
  const float qsc = (n0 < 1024) ? 0.125f : 1.0f;
#pragma unroll
  for (int fr = 0; fr < 8; ++fr) {
    const int row = m0 + wr * 128 + fr * 16 + g * 4;
#pragma unroll
    for (int fc = 0; fc < 4; ++fc) {
      const int col = n0 + wc * 64 + fc * 16 + c;
#pragma unroll
      for (int r = 0; r < 4; ++r)
        C[(size_t)(row + r) * E3 + col] = (bf16)(acc[fr][fc][r] * qsc);
    }
  }
}

// ---------------------------------------------------------------------------
// Kernel 4: out GEMM (128x128 tile, m97 structure) — unchanged.
// ---------------------------------------------------------------------------
template <int OUTMODE>
__global__ __launch_bounds__(256)
void gemm_bt(const bf16* __restrict__ A, const bf16* __restrict__ Bw,
             void* __restrict__ Cout, const float* __restrict__ bias, int ldc) {
  const int tid = threadIdx.x;
  const int w = tid >> 6;
  const int lane = tid & 63;
  const int c = lane & 15;
  const int g = lane >> 4;
  const int wr = w >> 1, wc = w & 1;
  const int m0 = blockIdx.y * 128;
  const int n0 = blockIdx.x * 128;

  __shared__ __align__(16) char smem[16384];
  char* As = smem;
  char* Bs = smem + 8192;

  f32x4 acc[4][4] = {};

  for (int kt = 0; kt < 1024; kt += 32) {
    __syncthreads();
#pragma unroll
    for (int it = 0; it < 2; ++it) {
      int t = it * 256 + tid;
      int row = t >> 2, cc = t & 3;
      gload_lds16(A + (size_t)(m0 + row) * 1024 + kt + cc * 8, As + it * 4096 + w * 1024);
      gload_lds16(Bw + (size_t)(n0 + row) * 1024 + kt + cc * 8, Bs + it * 4096 + w * 1024);
    }
    __syncthreads();

    bf16x8 af[4], bfr[4];
#pragma unroll
    for (int i = 0; i < 4; ++i)
      af[i] = *(const bf16x8*)(As + ((wr * 64 + i * 16 + c) * 32 + g * 8) * 2);
#pragma unroll
    for (int j = 0; j < 4; ++j)
      bfr[j] = *(const bf16x8*)(Bs + ((wc * 64 + j * 16 + c) * 32 + g * 8) * 2);
#pragma unroll
    for (int i = 0; i < 4; ++i)
#pragma unroll
      for (int j = 0; j < 4; ++j)
        acc[i][j] = __builtin_amdgcn_mfma_f32_16x16x32_bf16(af[i], bfr[j], acc[i][j], 0, 0, 0);
  }

  if (OUTMODE == 0) {
    const float qsc = (n0 < 1024) ? 0.125f : 1.0f;
    bf16* Cc = (bf16*)Cout;
#pragma unroll
    for (int i = 0; i < 4; ++i) {
      int row = m0 + wr * 64 + i * 16 + g * 4;
#pragma unroll
      for (int j = 0; j < 4; ++j) {
        int col = n0 + wc * 64 + j * 16 + c;
#pragma unroll
        for (int r = 0; r < 4; ++r)
          Cc[(size_t)(row + r) * ldc + col] = (bf16)(acc[i][j][r] * qsc);
      }
    }
  } else {
    float* Cc = (float*)Cout;
#pragma unroll
    for (int i = 0; i < 4; ++i) {
      int row = m0 + wr * 64 + i * 16 + g * 4;
#pragma unroll
      for (int j = 0; j < 4; ++j) {
        int col = n0 + wc * 64 + j * 16 + c;
        float bv = bias[col];
#pragma unroll
        for (int r = 0; r < 4; ++r)
          Cc[(size_t)(row + r) * ldc + col] = acc[i][j][r] + bv;
      }
    }
  }
}

// ---------------------------------------------------------------------------
// Kernel 3: fused flash attention — swapped-operand, 2-deep pipeline (T15).
// Unchanged from round 9 (passed @56.6us).
// ---------------------------------------------------------------------------
#define DSR128(dst, base, off) \
  asm volatile("ds_read_b128 %0, %1 offset:%c2" : "=v"(dst) : "v"(base), "i"(off))
#define DSTR(dst, base, off) \
  asm volatile("ds_read_b64_tr_b16 %0, %1 offset:%c2" : "=v"(dst) : "v"(base), "i"(off))

#define KF_ALL(KB) \
  DSR128(kf[0][0], kb0, (KB)*8192 + 0);    DSR128(kf[0][1], kb1, (KB)*8192 + 0); \
  DSR128(kf[1][0], kb0, (KB)*8192 + 2048); DSR128(kf[1][1], kb1, (KB)*8192 + 2048); \
  DSR128(kf[2][0], kb0, (KB)*8192 + 4096); DSR128(kf[2][1], kb1, (KB)*8192 + 4096); \
  DSR128(kf[3][0], kb0, (KB)*8192 + 6144); DSR128(kf[3][1], kb1, (KB)*8192 + 6144);

#define TRPAIR(f, ks, VP) \
  DSTR(tlo[f][ks], tb, (VP)*8192 + (f)*2048 + (ks)*1024); \
  DSTR(thi[f][ks], tb, (VP)*8192 + (f)*2048 + (ks)*1024 + 512);
#define TR_ALL(VP) \
  TRPAIR(0,0,VP) TRPAIR(0,1,VP) TRPAIR(1,0,VP) TRPAIR(1,1,VP) \
  TRPAIR(2,0,VP) TRPAIR(2,1,VP) TRPAIR(3,0,VP) TRPAIR(3,1,VP)

#define SMAX_A(SPRV, qc) { \
  f32x4 vm = SPRV[0][qc]; \
  _Pragma("unroll") for (int j = 1; j < 4; ++j) \
    _Pragma("unroll") for (int r = 0; r < 4; ++r) vm[r] = fmaxf(vm[r], SPRV[j][qc][r]); \
  float rmax = fmaxf(fmaxf(vm[0], vm[1]), fmaxf(vm[2], vm[3])); \
  rmax = fmaxf(rmax, __shfl_xor(rmax, 16, 64)); \
  rmax = fmaxf(rmax, __shfl_xor(rmax, 32, 64)); \
  const float rmax2 = rmax * LOG2E_; \
  if (!__all(rmax2 <= mrun[qc] + THR_)) { \
    const float mnew = fmaxf(mrun[qc], rmax2); \
    const float fac = __builtin_amdgcn_exp2f(mrun[qc] - mnew); \
    mrun[qc] = mnew; \
    _Pragma("unroll") for (int f = 0; f < 4; ++f) oacc[f][qc] *= fac; \
    lacc[qc] *= fac; \
  } }

#define SMAX_B(SPRV, qc) { \
  const float negm = -mrun[qc]; \
  f32x4 p[4]; \
  _Pragma("unroll") for (int j = 0; j < 4; ++j) \
    _Pragma("unroll") for (int r = 0; r < 4; ++r) \
      p[j][r] = __builtin_amdgcn_exp2f(fmaf(SPRV[j][qc][r], LOG2E_, negm)); \
  _Pragma("unroll") for (int ks = 0; ks < 2; ++ks) \
    _Pragma("unroll") for (int r = 0; r < 4; ++r) { \
      vb[qc][ks][r] = (bf16)p[ks][r]; vb[qc][ks][4 + r] = (bf16)p[ks + 2][r]; \
    } }

#define QK_ALL(SCUR) \
  _Pragma("unroll") for (int j = 0; j < 4; ++j) { \
    f32x4 z = {0.f, 0.f, 0.f, 0.f}; \
    f32x4 s0 = __builtin_amdgcn_mfma_f32_16x16x32_bf16(kf[j][0], qf[0][0], z, 0, 0, 0); \
    s0 = __builtin_amdgcn_mfma_f32_16x16x32_bf16(kf[j][1], qf[0][1], s0, 0, 0, 0); \
    SCUR[j][0] = s0; \
    f32x4 s1 = __builtin_amdgcn_mfma_f32_16x16x32_bf16(kf[j][0], qf[1][0], z, 0, 0, 0); \
    s1 = __builtin_amdgcn_mfma_f32_16x16x32_bf16(kf[j][1], qf[1][1], s1, 0, 0, 0); \
    SCUR[j][1] = s1; }

#define PV_ALL() \
  _Pragma("unroll") for (int f = 0; f < 4; ++f) \
    _Pragma("unroll") for (int ks = 0; ks < 2; ++ks) { \
      bf16x8 va; \
      _Pragma("unroll") for (int e = 0; e < 4; ++e) { va[e] = tlo[f][ks][e]; va[4+e] = thi[f][ks][e]; } \
      oacc[f][0] = __builtin_amdgcn_mfma_f32_16x16x32_bf16(va, vb[0][ks], oacc[f][0], 0, 0, 0); \
      oacc[f][1] = __builtin_amdgcn_mfma_f32_16x16x32_bf16(va, vb[1][ks], oacc[f][1], 0, 0, 0); \
    } \
  lacc[0] = __builtin_amdgcn_mfma_f32_16x16x32_bf16(ones, vb[0][0], lacc[0], 0, 0, 0); \
  lacc[0] = __builtin_amdgcn_mfma_f32_16x16x32_bf16(ones, vb[0][1], lacc[0], 0, 0, 0); \
  lacc[1] = __builtin_amdgcn_mfma_f32_16x16x32_bf16(ones, vb[1][0], lacc[1], 0, 0, 0); \
  lacc[1] = __builtin_amdgcn_mfma_f32_16x16x32_bf16(ones, vb[1][1], lacc[1], 0, 0, 0);

#define STEP(KB, VN, VP, SCUR, SPRV, DOSTAGE, DOPREV) { \
  if (DOSTAGE) { \
    gload_lds16(pK0, smem + ((KB)^1)*8192 + w*1024); \
    gload_lds16(pK1, smem + ((KB)^1)*8192 + 4096 + w*1024); \
    gload_lds16(pV0, smem + 16384 + (VN)*8192 + w*1024); \
    gload_lds16(pV1, smem + 16384 + (VN)*8192 + 4096 + w*1024); \
    pK0 += 64*E3; pK1 += 64*E3; pV0 += 64*E3; pV1 += 64*E3; \
  } \
  if (DOPREV) { SMAX_A(SPRV, 0); SMAX_A(SPRV, 1); } \
  __builtin_amdgcn_sched_barrier(0); \
  KF_ALL(KB); \
  if (DOPREV) { TR_ALL(VP); } \
  if (DOPREV) { SMAX_B(SPRV, 0); SMAX_B(SPRV, 1); } \
  if (DOPREV) { asm volatile("s_waitcnt lgkmcnt(15)" ::: "memory"); } \
  else        { asm volatile("s_waitcnt lgkmcnt(0)" ::: "memory"); } \
  __builtin_amdgcn_sched_barrier(0); \
  __builtin_amdgcn_s_setprio(1); \
  QK_ALL(SCUR); \
  __builtin_amdgcn_s_setprio(0); \
  if (DOPREV) { \
    asm volatile("s_waitcnt lgkmcnt(0)" ::: "memory"); \
    __builtin_amdgcn_sched_barrier(0); \
    __builtin_amdgcn_s_setprio(1); \
    PV_ALL(); \
    __builtin_amdgcn_s_setprio(0); \
  } \
  __syncthreads(); \
}

__global__ __launch_bounds__(256, 2)
void flash_attn(const bf16* __restrict__ qkv, bf16* __restrict__ attb) {
  int bid = blockIdx.x;
  bid = (bid & 7) * 64 + (bid >> 3);  // XCD chunk swizzle (512 % 8 == 0)
  const int tid = threadIdx.x;
  const int w = tid >> 6;
  const int lane = tid & 63;
  const int c = lane & 15;
  const int g = lane >> 4;
  const int qt = bid & 15;            // 16 q-tiles of 128 rows
  const int bh = bid >> 4;
  const int b = bh >> 4;
  const int h = bh & 15;
  const int q0 = qt * 128 + w * 32;

  __shared__ __align__(16) char smem[49152];
  const uint32_t smem32 = (uint32_t)(uintptr_t)smem;

  const uint32_t kb0 = smem32 + c * 128 + ((g ^ (c & 7)) * 16);
  const uint32_t kb1 = smem32 + c * 128 + (((4 + g) ^ (c & 7)) * 16);
  const uint32_t tb  = smem32 + 16384 + lane * 8;

  bf16x8 qf[2][2];
#pragma unroll
  for (int qc = 0; qc < 2; ++qc) {
    const size_t qbase = (size_t)(b * NN + q0 + qc * 16 + c) * E3 + h * 64;
    qf[qc][0] = *(const bf16x8*)(qkv + qbase + g * 8);
    qf[qc][1] = *(const bf16x8*)(qkv + qbase + 32 + g * 8);
  }

  bf16x8 ones;
#pragma unroll
  for (int e = 0; e < 8; ++e) ones[e] = (bf16)1.0f;

  const bf16 *pK0, *pK1, *pV0, *pV1;
  {
    int tK0 = tid, tK1 = 256 + tid;
    int r0 = tK0 >> 3, s0 = (tK0 & 7) ^ (r0 & 7);
    int r1 = tK1 >> 3, s1 = (tK1 & 7) ^ (r1 & 7);
    pK0 = qkv + (size_t)(b * NN + r0) * E3 + 1024 + h * 64 + s0 * 8;
    pK1 = qkv + (size_t)(b * NN + r1) * E3 + 1024 + h * 64 + s1 * 8;
    int sv0 = tid, sv1 = 256 + tid;
    int f0 = sv0 >> 7, ks0 = (sv0 >> 6) & 1, o0 = (sv0 >> 5) & 1,
        g0 = (sv0 >> 3) & 3, j0 = (sv0 >> 1) & 3, i0 = sv0 & 1;
    int f1 = sv1 >> 7, ks1 = (sv1 >> 6) & 1, o1 = (sv1 >> 5) & 1,
        g1 = (sv1 >> 3) & 3, j1 = (sv1 >> 1) & 3, i1 = sv1 & 1;
    int key0 = 32 * o0 + 16 * ks0 + 4 * g0 + j0;
    int key1 = 32 * o1 + 16 * ks1 + 4 * g1 + j1;
    pV0 = qkv + (size_t)(b * NN + key0) * E3 + 2048 + h * 64 + f0 * 16 + i0 * 8;
    pV1 = qkv + (size_t)(b * NN + key1) * E3 + 2048 + h * 64 + f1 * 16 + i1 * 8;
  }

  f32x4 oacc[4][2] = {};
  f32x4 lacc[2] = {};
  float mrun[2] = {-1e30f, -1e30f};
  f32x4 sA[4][2], sB[4][2];
  bf16x8 kf[4][2];
  bf16x4 tlo[4][2], thi[4][2];
  bf16x8 vb[2][2];

  gload_lds16(pK0, smem + w * 1024);
  gload_lds16(pK1, smem + 4096 + w * 1024);
  gload_lds16(pV0, smem + 16384 + w * 1024);
  gload_lds16(pV1, smem + 16384 + 4096 + w * 1024);
  pK0 += 64 * E3; pK1 += 64 * E3; pV0 += 64 * E3; pV1 += 64 * E3;
  __syncthreads();

  STEP(0, 1, 0, sA, sB, 1, 0)                 // t = 0
  for (int to = 1; to <= 25; to += 4) {
    STEP(1, 2, 0, sB, sA, 1, 1)               // t ≡ 1 (mod 4)
    STEP(0, 3, 1, sA, sB, 1, 1)               // t ≡ 2
    STEP(1, 0, 2, sB, sA, 1, 1)               // t ≡ 3
    STEP(0, 1, 3, sA, sB, 1, 1)               // t ≡ 0
  }
  STEP(1, 2, 0, sB, sA, 1, 1)                 // t = 29
  STEP(0, 3, 1, sA, sB, 1, 1)                 // t = 30
  STEP(1, 0, 2, sB, sA, 0, 1)                 // t = 31 (no stage)

  SMAX_A(sB, 0); SMAX_A(sB, 1);
  TR_ALL(3);
  SMAX_B(sB, 0); SMAX_B(sB, 1);
  asm volatile("s_waitcnt lgkmcnt(0)" ::: "memory");
  __builtin_amdgcn_sched_barrier(0);
  PV_ALL();

#pragma unroll
  for (int qc = 0; qc < 2; ++qc) {
    const float inv = __builtin_amdgcn_rcpf(lacc[qc][0]);
    const size_t row = (size_t)(b * NN + q0 + qc * 16 + c);
#pragma unroll
    for (int f = 0; f < 4; ++f) {
      bf16x4 o;
#pragma unroll
      for (int r = 0; r < 4; ++r) o[r] = (bf16)(oacc[f][qc][r] * inv);
      *(bf16x4*)(attb + row * 1024 + h * 64 + f * 16 + 4 * g) = o;
    }
  }
}

// ---------------------------------------------------------------------------
extern "C" void kernel_launch(void* const* d_in, const int* in_sizes, int n_in,
                              void* d_out, int out_size, void* d_ws, size_t ws_size,
                              hipStream_t stream) {
  const float* x = (const float*)d_in[0];
  const float* wqkv = (const float*)d_in[1];
  const float* wout = (const float*)d_in[2];
  const float* bout = (const float*)d_in[3];

  char* ws = (char*)d_ws;
  bf16* xb   = (bf16*)(ws);
  bf16* wqb  = (bf16*)(ws + 8388608);
  bf16* wob  = (bf16*)(ws + 14680064);
  bf16* qkvb = (bf16*)(ws + 16777216);
  bf16* attb = (bf16*)(ws + 41943040);

  convert_all<<<8192, 256, 0, stream>>>(x, wqkv, wout, xb, wqb, wob);
  gemm_qkv<<<192, 512, 0, stream>>>(xb, wqb, qkvb);
  flash_attn<<<512, 256, 0, stream>>>(qkvb, attb);
  gemm_bt<1><<<dim3(8, 32), 256, 0, stream>>>(attb, wob, d_out, bout, DIMM);
}

// Round 12
// 106.642 us; speedup vs baseline: 1.0794x; 1.0399x over previous
//
#include <hip/hip_runtime.h>
#include <hip/hip_bf16.h>
#include <stdint.h>

// Problem constants
#define BB 2
#define NN 2048
#define DIMM 1024
#define HEADS 16
#define DH 64
#define E3 3072   // 3*DIM
#define LOG2E_ 1.44269504088896f
#define THR_ 8.0f

typedef __bf16 bf16;
typedef __attribute__((ext_vector_type(8))) __bf16 bf16x8;
typedef __attribute__((ext_vector_type(4))) __bf16 bf16x4;
typedef __attribute__((ext_vector_type(4))) float f32x4;

// global -> LDS direct copy, 16B per lane. LDS dest must be wave-uniform base;
// HW adds lane*16. Global src is per-lane.
__device__ __forceinline__ void gload_lds16(const void* gsrc, void* ldst) {
  __builtin_amdgcn_global_load_lds(
      (const __attribute__((address_space(1))) uint32_t*)(uintptr_t)gsrc,
      (__attribute__((address_space(3))) uint32_t*)(uintptr_t)ldst,
      16, 0, 0);
}

// ---------------------------------------------------------------------------
// Kernel 1: fp32 -> bf16 conversion for x, w_qkv, w_out (fused)
// ---------------------------------------------------------------------------
__global__ __launch_bounds__(256)
void convert_all(const float* __restrict__ x, const float* __restrict__ wqkv,
                 const float* __restrict__ wout,
                 bf16* __restrict__ xb, bf16* __restrict__ wqb, bf16* __restrict__ wob) {
  size_t i = (size_t)blockIdx.x * blockDim.x + threadIdx.x;
  const float* src;
  bf16* dst;
  size_t off;
  if (i < 1048576u) { src = x; dst = xb; off = i; }
  else if (i < 1048576u + 786432u) { src = wqkv; dst = wqb; off = i - 1048576u; }
  else { src = wout; dst = wob; off = i - (1048576u + 786432u); }
  float4 v = ((const float4*)src)[off];
  bf16x4 o;
  o[0] = (bf16)v.x; o[1] = (bf16)v.y; o[2] = (bf16)v.z; o[3] = (bf16)v.w;
  *(bf16x4*)(dst + off * 4) = o;
}

// ---------------------------------------------------------------------------
// Kernel 2: qkv GEMM — 256x256 tile, BK=64 (128B rows), double-buffered.
// Unchanged from round 11 (passed).
// ---------------------------------------------------------------------------
#define GDSR(dst, base, off) \
  asm volatile("ds_read_b128 %0, %1 offset:%c2" : "=v"(dst) : "v"(base), "i"(off))

#define GRD12(ABASE, BBASE, OFF) \
  GDSR(af0, ABASE, (OFF));        GDSR(af1, ABASE, (OFF)+2048); \
  GDSR(af2, ABASE, (OFF)+4096);   GDSR(af3, ABASE, (OFF)+6144); \
  GDSR(af4, ABASE, (OFF)+8192);   GDSR(af5, ABASE, (OFF)+10240); \
  GDSR(af6, ABASE, (OFF)+12288);  GDSR(af7, ABASE, (OFF)+14336); \
  GDSR(bf0, BBASE, (OFF));        GDSR(bf1, BBASE, (OFF)+2048); \
  GDSR(bf2, BBASE, (OFF)+4096);   GDSR(bf3, BBASE, (OFF)+6144);

#define GMM32() \
  acc[0][0]=__builtin_amdgcn_mfma_f32_16x16x32_bf16(af0,bf0,acc[0][0],0,0,0); \
  acc[0][1]=__builtin_amdgcn_mfma_f32_16x16x32_bf16(af0,bf1,acc[0][1],0,0,0); \
  acc[0][2]=__builtin_amdgcn_mfma_f32_16x16x32_bf16(af0,bf2,acc[0][2],0,0,0); \
  acc[0][3]=__builtin_amdgcn_mfma_f32_16x16x32_bf16(af0,bf3,acc[0][3],0,0,0); \
  acc[1][0]=__builtin_amdgcn_mfma_f32_16x16x32_bf16(af1,bf0,acc[1][0],0,0,0); \
  acc[1][1]=__builtin_amdgcn_mfma_f32_16x16x32_bf16(af1,bf1,acc[1][1],0,0,0); \
  acc[1][2]=__builtin_amdgcn_mfma_f32_16x16x32_bf16(af1,bf2,acc[1][2],0,0,0); \
  acc[1][3]=__builtin_amdgcn_mfma_f32_16x16x32_bf16(af1,bf3,acc[1][3],0,0,0); \
  acc[2][0]=__builtin_amdgcn_mfma_f32_16x16x32_bf16(af2,bf0,acc[2][0],0,0,0); \
  acc[2][1]=__builtin_amdgcn_mfma_f32_16x16x32_bf16(af2,bf1,acc[2][1],0,0,0); \
  acc[2][2]=__builtin_amdgcn_mfma_f32_16x16x32_bf16(af2,bf2,acc[2][2],0,0,0); \
  acc[2][3]=__builtin_amdgcn_mfma_f32_16x16x32_bf16(af2,bf3,acc[2][3],0,0,0); \
  acc[3][0]=__builtin_amdgcn_mfma_f32_16x16x32_bf16(af3,bf0,acc[3][0],0,0,0); \
  acc[3][1]=__builtin_amdgcn_mfma_f32_16x16x32_bf16(af3,bf1,acc[3][1],0,0,0); \
  acc[3][2]=__builtin_amdgcn_mfma_f32_16x16x32_bf16(af3,bf2,acc[3][2],0,0,0); \
  acc[3][3]=__builtin_amdgcn_mfma_f32_16x16x32_bf16(af3,bf3,acc[3][3],0,0,0); \
  acc[4][0]=__builtin_amdgcn_mfma_f32_16x16x32_bf16(af4,bf0,acc[4][0],0,0,0); \
  acc[4][1]=__builtin_amdgcn_mfma_f32_16x16x32_bf16(af4,bf1,acc[4][1],0,0,0); \
  acc[4][2]=__builtin_amdgcn_mfma_f32_16x16x32_bf16(af4,bf2,acc[4][2],0,0,0); \
  acc[4][3]=__builtin_amdgcn_mfma_f32_16x16x32_bf16(af4,bf3,acc[4][3],0,0,0); \
  acc[5][0]=__builtin_amdgcn_mfma_f32_16x16x32_bf16(af5,bf0,acc[5][0],0,0,0); \
  acc[5][1]=__builtin_amdgcn_mfma_f32_16x16x32_bf16(af5,bf1,acc[5][1],0,0,0); \
  acc[5][2]=__builtin_amdgcn_mfma_f32_16x16x32_bf16(af5,bf2,acc[5][2],0,0,0); \
  acc[5][3]=__builtin_amdgcn_mfma_f32_16x16x32_bf16(af5,bf3,acc[5][3],0,0,0); \
  acc[6][0]=__builtin_amdgcn_mfma_f32_16x16x32_bf16(af6,bf0,acc[6][0],0,0,0); \
  acc[6][1]=__builtin_amdgcn_mfma_f32_16x16x32_bf16(af6,bf1,acc[6][1],0,0,0); \
  acc[6][2]=__builtin_amdgcn_mfma_f32_16x16x32_bf16(af6,bf2,acc[6][2],0,0,0); \
  acc[6][3]=__builtin_amdgcn_mfma_f32_16x16x32_bf16(af6,bf3,acc[6][3],0,0,0); \
  acc[7][0]=__builtin_amdgcn_mfma_f32_16x16x32_bf16(af7,bf0,acc[7][0],0,0,0); \
  acc[7][1]=__builtin_amdgcn_mfma_f32_16x16x32_bf16(af7,bf1,acc[7][1],0,0,0); \
  acc[7][2]=__builtin_amdgcn_mfma_f32_16x16x32_bf16(af7,bf2,acc[7][2],0,0,0); \
  acc[7][3]=__builtin_amdgcn_mfma_f32_16x16x32_bf16(af7,bf3,acc[7][3],0,0,0);

#define GSTAGE(BUF) { \
  gload_lds16(pA,          smem + (BUF)*32768 + w*1024); \
  gload_lds16(pA + 65536,  smem + (BUF)*32768 + 8192 + w*1024); \
  gload_lds16(pA + 131072, smem + (BUF)*32768 + 16384 + w*1024); \
  gload_lds16(pA + 196608, smem + (BUF)*32768 + 24576 + w*1024); \
  gload_lds16(pB,          smem + 65536 + (BUF)*32768 + w*1024); \
  gload_lds16(pB + 65536,  smem + 65536 + (BUF)*32768 + 8192 + w*1024); \
  gload_lds16(pB + 131072, smem + 65536 + (BUF)*32768 + 16384 + w*1024); \
  gload_lds16(pB + 196608, smem + 65536 + (BUF)*32768 + 24576 + w*1024); \
  pA += 64; pB += 64; }

#define GSTEP(BUF, DOSTAGE) { \
  bf16x8 af0, af1, af2, af3, af4, af5, af6, af7, bf0, bf1, bf2, bf3; \
  GRD12(abase0, bbase0, (BUF)*32768); \
  if (DOSTAGE) { GSTAGE((BUF)^1); } \
  asm volatile("s_waitcnt lgkmcnt(0)" ::: "memory"); \
  __builtin_amdgcn_sched_barrier(0); \
  __builtin_amdgcn_s_setprio(1); \
  GMM32(); \
  __builtin_amdgcn_s_setprio(0); \
  GRD12(abase1, bbase1, (BUF)*32768); \
  asm volatile("s_waitcnt lgkmcnt(0)" ::: "memory"); \
  __builtin_amdgcn_sched_barrier(0); \
  __builtin_amdgcn_s_setprio(1); \
  GMM32(); \
  __builtin_amdgcn_s_setprio(0); \
  if (DOSTAGE) { asm volatile("s_waitcnt vmcnt(0)" ::: "memory"); } \
  __builtin_amdgcn_sched_barrier(0); \
  __builtin_amdgcn_s_barrier(); \
}

__global__ __launch_bounds__(512, 2)
void gemm_qkv(const bf16* __restrict__ A, const bf16* __restrict__ Bw,
              bf16* __restrict__ C) {
  int bid = blockIdx.x;                 // 0..191
  bid = (bid & 7) * 24 + (bid >> 3);    // XCD chunk swizzle (192 % 8 == 0)
  const int nx = bid % 12;
  const int ny = bid / 12;
  const int m0 = ny * 256, n0 = nx * 256;
  const int tid = threadIdx.x;
  const int w = tid >> 6, lane = tid & 63, c = lane & 15, g = lane >> 4;
  const int wr = w >> 2, wc = w & 3;

  __shared__ __align__(16) char smem[131072];
  const uint32_t smem32 = (uint32_t)(uintptr_t)smem;
  const uint32_t abase0 = smem32 + (wr * 128 + c) * 128 + ((g ^ (c & 7)) * 16);
  const uint32_t abase1 = smem32 + (wr * 128 + c) * 128 + (((4 + g) ^ (c & 7)) * 16);
  const uint32_t bbase0 = smem32 + 65536 + (wc * 64 + c) * 128 + ((g ^ (c & 7)) * 16);
  const uint32_t bbase1 = smem32 + 65536 + (wc * 64 + c) * 128 + (((4 + g) ^ (c & 7)) * 16);

  const bf16 *pA, *pB;
  {
    const int r0 = tid >> 3;
    const int cc = (tid & 7) ^ ((tid >> 3) & 7);
    pA = A + (size_t)(m0 + r0) * 1024 + cc * 8;
    pB = Bw + (size_t)(n0 + r0) * 1024 + cc * 8;
  }

  f32x4 acc[8][4] = {};

  GSTAGE(0);
  asm volatile("s_waitcnt vmcnt(0)" ::: "memory");
  __builtin_amdgcn_sched_barrier(0);
  __builtin_amdgcn_s_barrier();

  for (int u = 0; u < 7; ++u) {   // t = 0..13
    GSTEP(0, 1) GSTEP(1, 1)
  }
  GSTEP(0, 1)   // t = 14 (stages tile 15 -> buf 1)
  GSTEP(1, 0)   // t = 15

  const float qsc = (n0 < 1024) ? 0.125f : 1.0f;
#pragma unroll
  for (int fr = 0; fr < 8; ++fr) {
    const int row = m0 + wr * 128 + fr * 16 + g * 4;
#pragma unroll
    for (int fc = 0; fc < 4; ++fc) {
      const int col = n0 + wc * 64 + fc * 16 + c;
#pragma unroll
      for (int r = 0; r < 4; ++r)
        C[(size_t)(row + r) * E3 + col] = (bf16)(acc[fr][fc][r] * qsc);
    }
  }
}

// ---------------------------------------------------------------------------
// Kernel 4 (NEW): out GEMM — 128x128 tile, BK=64 (128B rows), double-buffered,
// same swizzle/schedule family as gemm_qkv. Grid 8x32 = 256 blocks (full CU
// coverage). 256 thr = 4 waves (2M x 2N), per-wave 64x64 = 4x4 frags; per
// K-step 32 MFMA : 16 ds_read_b128, one raw s_barrier. LDS 64KB:
// A bufs @0/@16384, B bufs @32768/@49152. f32 output + bias.
// ---------------------------------------------------------------------------
#define ORD8(ABASE, BBASE, OFF) \
  GDSR(ao0, ABASE, (OFF));        GDSR(ao1, ABASE, (OFF)+2048); \
  GDSR(ao2, ABASE, (OFF)+4096);   GDSR(ao3, ABASE, (OFF)+6144); \
  GDSR(bo0, BBASE, (OFF));        GDSR(bo1, BBASE, (OFF)+2048); \
  GDSR(bo2, BBASE, (OFF)+4096);   GDSR(bo3, BBASE, (OFF)+6144);

#define OMM16() \
  acc[0][0]=__builtin_amdgcn_mfma_f32_16x16x32_bf16(ao0,bo0,acc[0][0],0,0,0); \
  acc[0][1]=__builtin_amdgcn_mfma_f32_16x16x32_bf16(ao0,bo1,acc[0][1],0,0,0); \
  acc[0][2]=__builtin_amdgcn_mfma_f32_16x16x32_bf16(ao0,bo2,acc[0][2],0,0,0); \
  acc[0][3]=__builtin_amdgcn_mfma_f32_16x16x32_bf16(ao0,bo3,acc[0][3],0,0,0); \
  acc[1][0]=__builtin_amdgcn_mfma_f32_16x16x32_bf16(ao1,bo0,acc[1][0],0,0,0); \
  acc[1][1]=__builtin_amdgcn_mfma_f32_16x16x32_bf16(ao1,bo1,acc[1][1],0,0,0); \
  acc[1][2]=__builtin_amdgcn_mfma_f32_16x16x32_bf16(ao1,bo2,acc[1][2],0,0,0); \
  acc[1][3]=__builtin_amdgcn_mfma_f32_16x16x32_bf16(ao1,bo3,acc[1][3],0,0,0); \
  acc[2][0]=__builtin_amdgcn_mfma_f32_16x16x32_bf16(ao2,bo0,acc[2][0],0,0,0); \
  acc[2][1]=__builtin_amdgcn_mfma_f32_16x16x32_bf16(ao2,bo1,acc[2][1],0,0,0); \
  acc[2][2]=__builtin_amdgcn_mfma_f32_16x16x32_bf16(ao2,bo2,acc[2][2],0,0,0); \
  acc[2][3]=__builtin_amdgcn_mfma_f32_16x16x32_bf16(ao2,bo3,acc[2][3],0,0,0); \
  acc[3][0]=__builtin_amdgcn_mfma_f32_16x16x32_bf16(ao3,bo0,acc[3][0],0,0,0); \
  acc[3][1]=__builtin_amdgcn_mfma_f32_16x16x32_bf16(ao3,bo1,acc[3][1],0,0,0); \
  acc[3][2]=__builtin_amdgcn_mfma_f32_16x16x32_bf16(ao3,bo2,acc[3][2],0,0,0); \
  acc[3][3]=__builtin_amdgcn_mfma_f32_16x16x32_bf16(ao3,bo3,acc[3][3],0,0,0);

#define OSTAGE(BUF) { \
  gload_lds16(pA,          smem + (BUF)*16384 + w*1024); \
  gload_lds16(pA + 32768,  smem + (BUF)*16384 + 4096 + w*1024); \
  gload_lds16(pA + 65536,  smem + (BUF)*16384 + 8192 + w*1024); \
  gload_lds16(pA + 98304,  smem + (BUF)*16384 + 12288 + w*1024); \
  gload_lds16(pB,          smem + 32768 + (BUF)*16384 + w*1024); \
  gload_lds16(pB + 32768,  smem + 32768 + (BUF)*16384 + 4096 + w*1024); \
  gload_lds16(pB + 65536,  smem + 32768 + (BUF)*16384 + 8192 + w*1024); \
  gload_lds16(pB + 98304,  smem + 32768 + (BUF)*16384 + 12288 + w*1024); \
  pA += 64; pB += 64; }

#define OSTEP(BUF, DOSTAGE) { \
  bf16x8 ao0, ao1, ao2, ao3, bo0, bo1, bo2, bo3; \
  ORD8(abase0, bbase0, (BUF)*16384); \
  if (DOSTAGE) { OSTAGE((BUF)^1); } \
  asm volatile("s_waitcnt lgkmcnt(0)" ::: "memory"); \
  __builtin_amdgcn_sched_barrier(0); \
  __builtin_amdgcn_s_setprio(1); \
  OMM16(); \
  __builtin_amdgcn_s_setprio(0); \
  ORD8(abase1, bbase1, (BUF)*16384); \
  asm volatile("s_waitcnt lgkmcnt(0)" ::: "memory"); \
  __builtin_amdgcn_sched_barrier(0); \
  __builtin_amdgcn_s_setprio(1); \
  OMM16(); \
  __builtin_amdgcn_s_setprio(0); \
  if (DOSTAGE) { asm volatile("s_waitcnt vmcnt(0)" ::: "memory"); } \
  __builtin_amdgcn_sched_barrier(0); \
  __builtin_amdgcn_s_barrier(); \
}

__global__ __launch_bounds__(256, 2)
void gemm_out(const bf16* __restrict__ A, const bf16* __restrict__ Bw,
              float* __restrict__ C, const float* __restrict__ bias) {
  int bid = blockIdx.x;                 // 0..255
  bid = (bid & 7) * 32 + (bid >> 3);    // XCD chunk swizzle (256 % 8 == 0)
  const int nx = bid & 7;               // 8 col tiles
  const int ny = bid >> 3;              // 32 row tiles
  const int m0 = ny * 128, n0 = nx * 128;
  const int tid = threadIdx.x;
  const int w = tid >> 6, lane = tid & 63, c = lane & 15, g = lane >> 4;
  const int wr = w >> 1, wc = w & 1;

  __shared__ __align__(16) char smem[65536];
  const uint32_t smem32 = (uint32_t)(uintptr_t)smem;
  const uint32_t abase0 = smem32 + (wr * 64 + c) * 128 + ((g ^ (c & 7)) * 16);
  const uint32_t abase1 = smem32 + (wr * 64 + c) * 128 + (((4 + g) ^ (c & 7)) * 16);
  const uint32_t bbase0 = smem32 + 32768 + (wc * 64 + c) * 128 + ((g ^ (c & 7)) * 16);
  const uint32_t bbase1 = smem32 + 32768 + (wc * 64 + c) * 128 + (((4 + g) ^ (c & 7)) * 16);

  // staging src: dest byte = it*4096 + tid*16 -> row = it*32 + (tid>>3),
  // stored chunk tid&7, logical chunk cc = (tid&7) ^ ((tid>>3)&7).
  const bf16 *pA, *pB;
  {
    const int r0 = tid >> 3;
    const int cc = (tid & 7) ^ ((tid >> 3) & 7);
    pA = A + (size_t)(m0 + r0) * 1024 + cc * 8;
    pB = Bw + (size_t)(n0 + r0) * 1024 + cc * 8;
  }

  f32x4 acc[4][4] = {};

  OSTAGE(0);
  asm volatile("s_waitcnt vmcnt(0)" ::: "memory");
  __builtin_amdgcn_sched_barrier(0);
  __builtin_amdgcn_s_barrier();

  for (int u = 0; u < 7; ++u) {   // t = 0..13
    OSTEP(0, 1) OSTEP(1, 1)
  }
  OSTEP(0, 1)   // t = 14 (stages tile 15 -> buf 1)
  OSTEP(1, 0)   // t = 15

  // epilogue: C/D frag layout col = lane&15, row = (lane>>4)*4 + reg
#pragma unroll
  for (int i = 0; i < 4; ++i) {
    const int row = m0 + wr * 64 + i * 16 + g * 4;
#pragma unroll
    for (int j = 0; j < 4; ++j) {
      const int col = n0 + wc * 64 + j * 16 + c;
      const float bv = bias[col];
#pragma unroll
      for (int r = 0; r < 4; ++r)
        C[(size_t)(row + r) * DIMM + col] = acc[i][j][r] + bv;
    }
  }
}

// ---------------------------------------------------------------------------
// Kernel 3: fused flash attention — swapped-operand, 2-deep pipeline (T15).
// Unchanged from round 9 (passed @56.6us).
// ---------------------------------------------------------------------------
#define DSR128(dst, base, off) \
  asm volatile("ds_read_b128 %0, %1 offset:%c2" : "=v"(dst) : "v"(base), "i"(off))
#define DSTR(dst, base, off) \
  asm volatile("ds_read_b64_tr_b16 %0, %1 offset:%c2" : "=v"(dst) : "v"(base), "i"(off))

#define KF_ALL(KB) \
  DSR128(kf[0][0], kb0, (KB)*8192 + 0);    DSR128(kf[0][1], kb1, (KB)*8192 + 0); \
  DSR128(kf[1][0], kb0, (KB)*8192 + 2048); DSR128(kf[1][1], kb1, (KB)*8192 + 2048); \
  DSR128(kf[2][0], kb0, (KB)*8192 + 4096); DSR128(kf[2][1], kb1, (KB)*8192 + 4096); \
  DSR128(kf[3][0], kb0, (KB)*8192 + 6144); DSR128(kf[3][1], kb1, (KB)*8192 + 6144);

#define TRPAIR(f, ks, VP) \
  DSTR(tlo[f][ks], tb, (VP)*8192 + (f)*2048 + (ks)*1024); \
  DSTR(thi[f][ks], tb, (VP)*8192 + (f)*2048 + (ks)*1024 + 512);
#define TR_ALL(VP) \
  TRPAIR(0,0,VP) TRPAIR(0,1,VP) TRPAIR(1,0,VP) TRPAIR(1,1,VP) \
  TRPAIR(2,0,VP) TRPAIR(2,1,VP) TRPAIR(3,0,VP) TRPAIR(3,1,VP)

#define SMAX_A(SPRV, qc) { \
  f32x4 vm = SPRV[0][qc]; \
  _Pragma("unroll") for (int j = 1; j < 4; ++j) \
    _Pragma("unroll") for (int r = 0; r < 4; ++r) vm[r] = fmaxf(vm[r], SPRV[j][qc][r]); \
  float rmax = fmaxf(fmaxf(vm[0], vm[1]), fmaxf(vm[2], vm[3])); \
  rmax = fmaxf(rmax, __shfl_xor(rmax, 16, 64)); \
  rmax = fmaxf(rmax, __shfl_xor(rmax, 32, 64)); \
  const float rmax2 = rmax * LOG2E_; \
  if (!__all(rmax2 <= mrun[qc] + THR_)) { \
    const float mnew = fmaxf(mrun[qc], rmax2); \
    const float fac = __builtin_amdgcn_exp2f(mrun[qc] - mnew); \
    mrun[qc] = mnew; \
    _Pragma("unroll") for (int f = 0; f < 4; ++f) oacc[f][qc] *= fac; \
    lacc[qc] *= fac; \
  } }

#define SMAX_B(SPRV, qc) { \
  const float negm = -mrun[qc]; \
  f32x4 p[4]; \
  _Pragma("unroll") for (int j = 0; j < 4; ++j) \
    _Pragma("unroll") for (int r = 0; r < 4; ++r) \
      p[j][r] = __builtin_amdgcn_exp2f(fmaf(SPRV[j][qc][r], LOG2E_, negm)); \
  _Pragma("unroll") for (int ks = 0; ks < 2; ++ks) \
    _Pragma("unroll") for (int r = 0; r < 4; ++r) { \
      vb[qc][ks][r] = (bf16)p[ks][r]; vb[qc][ks][4 + r] = (bf16)p[ks + 2][r]; \
    } }

#define QK_ALL(SCUR) \
  _Pragma("unroll") for (int j = 0; j < 4; ++j) { \
    f32x4 z = {0.f, 0.f, 0.f, 0.f}; \
    f32x4 s0 = __builtin_amdgcn_mfma_f32_16x16x32_bf16(kf[j][0], qf[0][0], z, 0, 0, 0); \
    s0 = __builtin_amdgcn_mfma_f32_16x16x32_bf16(kf[j][1], qf[0][1], s0, 0, 0, 0); \
    SCUR[j][0] = s0; \
    f32x4 s1 = __builtin_amdgcn_mfma_f32_16x16x32_bf16(kf[j][0], qf[1][0], z, 0, 0, 0); \
    s1 = __builtin_amdgcn_mfma_f32_16x16x32_bf16(kf[j][1], qf[1][1], s1, 0, 0, 0); \
    SCUR[j][1] = s1; }

#define PV_ALL() \
  _Pragma("unroll") for (int f = 0; f < 4; ++f) \
    _Pragma("unroll") for (int ks = 0; ks < 2; ++ks) { \
      bf16x8 va; \
      _Pragma("unroll") for (int e = 0; e < 4; ++e) { va[e] = tlo[f][ks][e]; va[4+e] = thi[f][ks][e]; } \
      oacc[f][0] = __builtin_amdgcn_mfma_f32_16x16x32_bf16(va, vb[0][ks], oacc[f][0], 0, 0, 0); \
      oacc[f][1] = __builtin_amdgcn_mfma_f32_16x16x32_bf16(va, vb[1][ks], oacc[f][1], 0, 0, 0); \
    } \
  lacc[0] = __builtin_amdgcn_mfma_f32_16x16x32_bf16(ones, vb[0][0], lacc[0], 0, 0, 0); \
  lacc[0] = __builtin_amdgcn_mfma_f32_16x16x32_bf16(ones, vb[0][1], lacc[0], 0, 0, 0); \
  lacc[1] = __builtin_amdgcn_mfma_f32_16x16x32_bf16(ones, vb[1][0], lacc[1], 0, 0, 0); \
  lacc[1] = __builtin_amdgcn_mfma_f32_16x16x32_bf16(ones, vb[1][1], lacc[1], 0, 0, 0);

#define STEP(KB, VN, VP, SCUR, SPRV, DOSTAGE, DOPREV) { \
  if (DOSTAGE) { \
    gload_lds16(pK0, smem + ((KB)^1)*8192 + w*1024); \
    gload_lds16(pK1, smem + ((KB)^1)*8192 + 4096 + w*1024); \
    gload_lds16(pV0, smem + 16384 + (VN)*8192 + w*1024); \
    gload_lds16(pV1, smem + 16384 + (VN)*8192 + 4096 + w*1024); \
    pK0 += 64*E3; pK1 += 64*E3; pV0 += 64*E3; pV1 += 64*E3; \
  } \
  if (DOPREV) { SMAX_A(SPRV, 0); SMAX_A(SPRV, 1); } \
  __builtin_amdgcn_sched_barrier(0); \
  KF_ALL(KB); \
  if (DOPREV) { TR_ALL(VP); } \
  if (DOPREV) { SMAX_B(SPRV, 0); SMAX_B(SPRV, 1); } \
  if (DOPREV) { asm volatile("s_waitcnt lgkmcnt(15)" ::: "memory"); } \
  else        { asm volatile("s_waitcnt lgkmcnt(0)" ::: "memory"); } \
  __builtin_amdgcn_sched_barrier(0); \
  __builtin_amdgcn_s_setprio(1); \
  QK_ALL(SCUR); \
  __builtin_amdgcn_s_setprio(0); \
  if (DOPREV) { \
    asm volatile("s_waitcnt lgkmcnt(0)" ::: "memory"); \
    __builtin_amdgcn_sched_barrier(0); \
    __builtin_amdgcn_s_setprio(1); \
    PV_ALL(); \
    __builtin_amdgcn_s_setprio(0); \
  } \
  __syncthreads(); \
}

__global__ __launch_bounds__(256, 2)
void flash_attn(const bf16* __restrict__ qkv, bf16* __restrict__ attb) {
  int bid = blockIdx.x;
  bid = (bid & 7) * 64 + (bid >> 3);  // XCD chunk swizzle (512 % 8 == 0)
  const int tid = threadIdx.x;
  const int w = tid >> 6;
  const int lane = tid & 63;
  const int c = lane & 15;
  const int g = lane >> 4;
  const int qt = bid & 15;            // 16 q-tiles of 128 rows
  const int bh = bid >> 4;
  const int b = bh >> 4;
  const int h = bh & 15;
  const int q0 = qt * 128 + w * 32;

  __shared__ __align__(16) char smem[49152];
  const uint32_t smem32 = (uint32_t)(uintptr_t)smem;

  const uint32_t kb0 = smem32 + c * 128 + ((g ^ (c & 7)) * 16);
  const uint32_t kb1 = smem32 + c * 128 + (((4 + g) ^ (c & 7)) * 16);
  const uint32_t tb  = smem32 + 16384 + lane * 8;

  bf16x8 qf[2][2];
#pragma unroll
  for (int qc = 0; qc < 2; ++qc) {
    const size_t qbase = (size_t)(b * NN + q0 + qc * 16 + c) * E3 + h * 64;
    qf[qc][0] = *(const bf16x8*)(qkv + qbase + g * 8);
    qf[qc][1] = *(const bf16x8*)(qkv + qbase + 32 + g * 8);
  }

  bf16x8 ones;
#pragma unroll
  for (int e = 0; e < 8; ++e) ones[e] = (bf16)1.0f;

  const bf16 *pK0, *pK1, *pV0, *pV1;
  {
    int tK0 = tid, tK1 = 256 + tid;
    int r0 = tK0 >> 3, s0 = (tK0 & 7) ^ (r0 & 7);
    int r1 = tK1 >> 3, s1 = (tK1 & 7) ^ (r1 & 7);
    pK0 = qkv + (size_t)(b * NN + r0) * E3 + 1024 + h * 64 + s0 * 8;
    pK1 = qkv + (size_t)(b * NN + r1) * E3 + 1024 + h * 64 + s1 * 8;
    int sv0 = tid, sv1 = 256 + tid;
    int f0 = sv0 >> 7, ks0 = (sv0 >> 6) & 1, o0 = (sv0 >> 5) & 1,
        g0 = (sv0 >> 3) & 3, j0 = (sv0 >> 1) & 3, i0 = sv0 & 1;
    int f1 = sv1 >> 7, ks1 = (sv1 >> 6) & 1, o1 = (sv1 >> 5) & 1,
        g1 = (sv1 >> 3) & 3, j1 = (sv1 >> 1) & 3, i1 = sv1 & 1;
    int key0 = 32 * o0 + 16 * ks0 + 4 * g0 + j0;
    int key1 = 32 * o1 + 16 * ks1 + 4 * g1 + j1;
    pV0 = qkv + (size_t)(b * NN + key0) * E3 + 2048 + h * 64 + f0 * 16 + i0 * 8;
    pV1 = qkv + (size_t)(b * NN + key1) * E3 + 2048 + h * 64 + f1 * 16 + i1 * 8;
  }

  f32x4 oacc[4][2] = {};
  f32x4 lacc[2] = {};
  float mrun[2] = {-1e30f, -1e30f};
  f32x4 sA[4][2], sB[4][2];
  bf16x8 kf[4][2];
  bf16x4 tlo[4][2], thi[4][2];
  bf16x8 vb[2][2];

  gload_lds16(pK0, smem + w * 1024);
  gload_lds16(pK1, smem + 4096 + w * 1024);
  gload_lds16(pV0, smem + 16384 + w * 1024);
  gload_lds16(pV1, smem + 16384 + 4096 + w * 1024);
  pK0 += 64 * E3; pK1 += 64 * E3; pV0 += 64 * E3; pV1 += 64 * E3;
  __syncthreads();

  STEP(0, 1, 0, sA, sB, 1, 0)                 // t = 0
  for (int to = 1; to <= 25; to += 4) {
    STEP(1, 2, 0, sB, sA, 1, 1)               // t ≡ 1 (mod 4)
    STEP(0, 3, 1, sA, sB, 1, 1)               // t ≡ 2
    STEP(1, 0, 2, sB, sA, 1, 1)               // t ≡ 3
    STEP(0, 1, 3, sA, sB, 1, 1)               // t ≡ 0
  }
  STEP(1, 2, 0, sB, sA, 1, 1)                 // t = 29
  STEP(0, 3, 1, sA, sB, 1, 1)                 // t = 30
  STEP(1, 0, 2, sB, sA, 0, 1)                 // t = 31 (no stage)

  SMAX_A(sB, 0); SMAX_A(sB, 1);
  TR_ALL(3);
  SMAX_B(sB, 0); SMAX_B(sB, 1);
  asm volatile("s_waitcnt lgkmcnt(0)" ::: "memory");
  __builtin_amdgcn_sched_barrier(0);
  PV_ALL();

#pragma unroll
  for (int qc = 0; qc < 2; ++qc) {
    const float inv = __builtin_amdgcn_rcpf(lacc[qc][0]);
    const size_t row = (size_t)(b * NN + q0 + qc * 16 + c);
#pragma unroll
    for (int f = 0; f < 4; ++f) {
      bf16x4 o;
#pragma unroll
      for (int r = 0; r < 4; ++r) o[r] = (bf16)(oacc[f][qc][r] * inv);
      *(bf16x4*)(attb + row * 1024 + h * 64 + f * 16 + 4 * g) = o;
    }
  }
}

// ---------------------------------------------------------------------------
extern "C" void kernel_launch(void* const* d_in, const int* in_sizes, int n_in,
                              void* d_out, int out_size, void* d_ws, size_t ws_size,
                              hipStream_t stream) {
  const float* x = (const float*)d_in[0];
  const float* wqkv = (const float*)d_in[1];
  const float* wout = (const float*)d_in[2];
  const float* bout = (const float*)d_in[3];

  char* ws = (char*)d_ws;
  bf16* xb   = (bf16*)(ws);
  bf16* wqb  = (bf16*)(ws + 8388608);
  bf16* wob  = (bf16*)(ws + 14680064);
  bf16* qkvb = (bf16*)(ws + 16777216);
  bf16* attb = (bf16*)(ws + 41943040);

  convert_all<<<8192, 256, 0, stream>>>(x, wqkv, wout, xb, wqb, wob);
  gemm_qkv<<<192, 512, 0, stream>>>(xb, wqb, qkvb);
  flash_attn<<<512, 256, 0, stream>>>(qkvb, attb);
  gemm_out<<<256, 256, 0, stream>>>(attb, wob, (float*)d_out, bout);
}